// Round 5
// baseline (3042.210 us; speedup 1.0000x reference)
//
#include <hip/hip_runtime.h>
#include <math.h>

#define B       32
#define S_FULL  512
#define S       511            // sliced length (drop token 0)
#define D       768
#define NROWS   (B * S)        // 16352

#define TM 128
#define TN 128
#define NCHUNK 4
#define NKT 24                 // D / 32
#define RSTR 72                // LDS row stride in halfwords (144 B, 16B-aligned)
#define EPS_MARGIN 5e-4f       // split-bf16 sim error ~1e-5; 50x safety

typedef __attribute__((ext_vector_type(8))) short bf16x8;   // 8 bf16 (4 VGPRs)
typedef __attribute__((ext_vector_type(4))) float f32x4;

__device__ inline unsigned short f2bf(float f) {
    union { float f; unsigned u; } c; c.f = f;
    unsigned u = c.u;
    return (unsigned short)((u + 0x7fffu + ((u >> 16) & 1u)) >> 16);   // RNE
}
__device__ inline float bf2f(unsigned short h) {
    union { unsigned u; float f; } c; c.u = ((unsigned)h) << 16;
    return c.f;
}
__device__ inline void split4(float x0, float x1, float x2, float x3,
                              short4& hi, short4& lo) {
    unsigned short h0 = f2bf(x0), h1 = f2bf(x1), h2 = f2bf(x2), h3 = f2bf(x3);
    hi = make_short4((short)h0, (short)h1, (short)h2, (short)h3);
    lo = make_short4((short)f2bf(x0 - bf2f(h0)), (short)f2bf(x1 - bf2f(h1)),
                     (short)f2bf(x2 - bf2f(h2)), (short)f2bf(x3 - bf2f(h3)));
}

// ---------------- 1. prep: row inv-norms + image loss (shares target read) --
__global__ __launch_bounds__(256) void prep_kernel(
    const float* __restrict__ image, const float* __restrict__ text,
    const float* __restrict__ target,
    float* __restrict__ inv_t, float* __restrict__ inv_g, float* __restrict__ acc)
{
    int row  = blockIdx.x * 4 + (threadIdx.x >> 6);   // 0..B*S_FULL-1
    int lane = threadIdx.x & 63;
    int b = row >> 9, i = row & 511;
    const float4* pi4 = (const float4*)(image  + (size_t)row * D);
    const float4* pt4 = (const float4*)(text   + (size_t)row * D);
    const float4* pg4 = (const float4*)(target + (size_t)row * D);
    float st = 0.f, sg = 0.f, si = 0.f;
    #pragma unroll
    for (int q = 0; q < 3; ++q) {
        float4 a = pt4[lane + 64 * q];
        float4 g = pg4[lane + 64 * q];
        float4 m = pi4[lane + 64 * q];
        st += a.x*a.x + a.y*a.y + a.z*a.z + a.w*a.w;
        sg += g.x*g.x + g.y*g.y + g.z*g.z + g.w*g.w;
        float dx = m.x-g.x, dy = m.y-g.y, dz = m.z-g.z, dw = m.w-g.w;
        si += dx*dx + dy*dy + dz*dz + dw*dw;
    }
    #pragma unroll
    for (int m = 32; m > 0; m >>= 1) {
        st += __shfl_xor(st, m); sg += __shfl_xor(sg, m); si += __shfl_xor(si, m);
    }
    if (lane == 0) {
        atomicAdd(&acc[blockIdx.x & 63], si);
        if (i >= 1) {
            int r = b * S + i - 1;
            inv_t[r] = (st > 0.f) ? 1.f / sqrtf(st) : 0.f;
            inv_g[r] = (sg > 0.f) ? 1.f / sqrtf(sg) : 0.f;
        }
    }
}

// ---------------- 2. split-bf16 MFMA GEMM + per-chunk top-2 ----------------
// grid (4, NCHUNK, B); block 256 (4 waves); block tile 128x128.
// Wave grid 4x1: wave w owns rows [w*32, w*32+32) x ALL 128 cols -> each
// output slot has exactly ONE writer (fixes round-3 wx-race).
__global__ __launch_bounds__(256, 2) void simargmax_kernel(
    const float* __restrict__ text, const float* __restrict__ target,
    const float* __restrict__ inv_t, const float* __restrict__ inv_g,
    float* __restrict__ pv, float* __restrict__ ps, int* __restrict__ pj)
{
    __shared__ __align__(16) short As[TM * RSTR];   // per row: [32 hi][32 lo] bf16
    __shared__ __align__(16) short Bs[TM * RSTR];

    const int i0 = blockIdx.x * TM;
    const int jc = blockIdx.y;
    const int j0 = jc * TN;
    const int b  = blockIdx.z;
    const int t  = threadIdx.x;
    const int lane = t & 63;
    const int wy = t >> 6;                    // wave row-strip 0..3
    const int quad = lane >> 4, cid = lane & 15;

    const float* Abase = text   + (size_t)b * S_FULL * D + D;   // skip token 0
    const float* Bbase = target + (size_t)b * S_FULL * D + D;

    // staging map: 8 lanes x float4 = 128B contiguous per row
    const int r0 = t >> 3;          // 0..31
    const int kq = (t & 7) * 4;     // 0..28

    float sa[4], sb[4];
    #pragma unroll
    for (int h = 0; h < 4; ++h) {
        int gi = i0 + r0 + h * 32;
        sa[h] = (gi < S) ? inv_t[b * S + gi] : 0.f;
        int gj = j0 + r0 + h * 32;
        sb[h] = (gj < S) ? inv_g[b * S + gj] : 0.f;
    }

    f32x4 acc[2][8];
    #pragma unroll
    for (int mt = 0; mt < 2; ++mt)
        #pragma unroll
        for (int nt = 0; nt < 8; ++nt)
            acc[mt][nt] = (f32x4){0.f, 0.f, 0.f, 0.f};

    for (int kt = 0; kt < NKT; ++kt) {
        const int k0 = kt * 32;
        float4 va[4], vb[4];
        #pragma unroll
        for (int h = 0; h < 4; ++h) {
            int gi = i0 + r0 + h * 32;
            va[h] = (gi < S) ? *(const float4*)(Abase + (size_t)gi * D + k0 + kq)
                             : make_float4(0.f, 0.f, 0.f, 0.f);
            int gj = j0 + r0 + h * 32;
            vb[h] = (gj < S) ? *(const float4*)(Bbase + (size_t)gj * D + k0 + kq)
                             : make_float4(0.f, 0.f, 0.f, 0.f);
        }
        __syncthreads();   // prior tile's ds_reads drained before overwrite
        #pragma unroll
        for (int h = 0; h < 4; ++h) {
            int row = r0 + h * 32;
            short4 ahi, alo, bhi, blo;
            split4(va[h].x * sa[h], va[h].y * sa[h], va[h].z * sa[h], va[h].w * sa[h], ahi, alo);
            split4(vb[h].x * sb[h], vb[h].y * sb[h], vb[h].z * sb[h], vb[h].w * sb[h], bhi, blo);
            *(short4*)&As[row * RSTR + kq]      = ahi;
            *(short4*)&As[row * RSTR + 32 + kq] = alo;
            *(short4*)&Bs[row * RSTR + kq]      = bhi;
            *(short4*)&Bs[row * RSTR + 32 + kq] = blo;
        }
        __syncthreads();

        bf16x8 ah[2], al[2];
        #pragma unroll
        for (int mt = 0; mt < 2; ++mt) {
            int ad = (wy * 32 + mt * 16 + cid) * RSTR + quad * 8;
            ah[mt] = *(const bf16x8*)&As[ad];
            al[mt] = *(const bf16x8*)&As[ad + 32];
        }
        #pragma unroll
        for (int nt = 0; nt < 8; ++nt) {
            int bd = (nt * 16 + cid) * RSTR + quad * 8;
            bf16x8 bh = *(const bf16x8*)&Bs[bd];
            bf16x8 bl = *(const bf16x8*)&Bs[bd + 32];
            #pragma unroll
            for (int mt = 0; mt < 2; ++mt) {
                acc[mt][nt] = __builtin_amdgcn_mfma_f32_16x16x32_bf16(ah[mt], bh, acc[mt][nt], 0, 0, 0);
                acc[mt][nt] = __builtin_amdgcn_mfma_f32_16x16x32_bf16(ah[mt], bl, acc[mt][nt], 0, 0, 0);
                acc[mt][nt] = __builtin_amdgcn_mfma_f32_16x16x32_bf16(al[mt], bh, acc[mt][nt], 0, 0, 0);
            }
        }
    }

    // epilogue: per-row top-2 over this chunk's 128 cols.
    // C/D layout: col = cid (within n-tile), row = quad*4 + reg (within m-tile)
    #pragma unroll
    for (int mt = 0; mt < 2; ++mt) {
        #pragma unroll
        for (int r = 0; r < 4; ++r) {
            float v1 = -INFINITY, v2 = -INFINITY; int j1 = -1;
            #pragma unroll
            for (int nt = 0; nt < 8; ++nt) {
                int col = j0 + nt * 16 + cid;
                float v = acc[mt][nt][r];
                if (col < S) {
                    if (v > v1) { v2 = v1; v1 = v; j1 = col; }
                    else if (v > v2) v2 = v;
                }
            }
            #pragma unroll
            for (int m = 1; m < 16; m <<= 1) {
                float ov1 = __shfl_xor(v1, m);
                int   oj1 = __shfl_xor(j1, m);
                float ov2 = __shfl_xor(v2, m);
                if (ov1 > v1) { v2 = fmaxf(v1, ov2); v1 = ov1; j1 = oj1; }
                else          { v2 = fmaxf(v2, ov1); }
            }
            if (cid == 0) {
                int gi = i0 + wy * 32 + mt * 16 + quad * 4 + r;
                if (gi < S) {
                    size_t o = ((size_t)(b * S + gi) << 2) + jc;
                    pv[o] = v1; ps[o] = v2; pj[o] = j1;
                }
            }
        }
    }
}

// ---------------- 3. combine chunks; commit or flag; text loss ----------------
__global__ __launch_bounds__(256) void text_kernel(
    const float* __restrict__ text, const float* __restrict__ target,
    const int* __restrict__ pm,
    const float* __restrict__ pv, const float* __restrict__ ps, const int* __restrict__ pj,
    float* __restrict__ idx_f, float* __restrict__ acc,
    int* __restrict__ list, int* __restrict__ cnt)
{
    int row = blockIdx.x * 4 + (threadIdx.x >> 6);
    if (row >= NROWS) return;
    int lane = threadIdx.x & 63;
    int b = row / S, i = row - b * S;

    float v1 = -INFINITY, v2 = -INFINITY; int j1 = 0;
    #pragma unroll
    for (int c = 0; c < NCHUNK; ++c) {
        size_t o = ((size_t)row << 2) + c;
        float a1 = pv[o], a2 = ps[o]; int aj = pj[o];
        if (a1 > v1) { v2 = fmaxf(v1, a2); v1 = a1; j1 = aj; }
        else         { v2 = fmaxf(v2, a1); }
    }
    if (v1 - v2 < EPS_MARGIN) {          // too close for split-bf16: exact recheck
        if (lane == 0) { int p = atomicAdd(cnt, 1); list[p] = row; }
        return;
    }
    if (lane == 0) idx_f[row] = (float)j1;

    if (pm[b * S_FULL + i + 1] != 0) return;
    const float4* pt = (const float4*)(text   + (size_t)(b * S_FULL + i  + 1) * D);
    const float4* pg = (const float4*)(target + (size_t)(b * S_FULL + j1 + 1) * D);
    float s = 0.f;
    #pragma unroll
    for (int q = 0; q < 3; ++q) {
        float4 a = pt[lane + 64 * q];
        float4 g = pg[lane + 64 * q];
        float dx = a.x-g.x, dy = a.y-g.y, dz = a.z-g.z, dw = a.w-g.w;
        s += dx*dx + dy*dy + dz*dz + dw*dw;
    }
    #pragma unroll
    for (int m = 32; m > 0; m >>= 1) s += __shfl_xor(s, m);
    if (lane == 0) {
        atomicAdd(&acc[64  + (blockIdx.x & 63)], s);
        atomicAdd(&acc[128 + (blockIdx.x & 63)], 1.0f);
    }
}

// ---------------- 4. exact fp32 argmax re-check for flagged rows ----------------
__global__ __launch_bounds__(256) void recheck_kernel(
    const float* __restrict__ text, const float* __restrict__ target,
    const int* __restrict__ pm, const float* __restrict__ inv_g,
    const int* __restrict__ list, const int* __restrict__ cnt,
    float* __restrict__ idx_f, float* __restrict__ acc)
{
    __shared__ float trow[D];
    __shared__ float wv[4];
    __shared__ int   wj[4];
    __shared__ int   bjf;
    __shared__ float ls[4];
    const int t = threadIdx.x, w = t >> 6, lane = t & 63;
    const int n = *cnt;
    for (int it = blockIdx.x; it < n; it += gridDim.x) {
        int row = list[it];
        int b = row / S, i = row - b * S;
        const float* tp = text + (size_t)(b * S_FULL + i + 1) * D;
        __syncthreads();
        for (int d = t; d < D; d += 256) trow[d] = tp[d];
        __syncthreads();
        float bv = -INFINITY; int bj = 0;
        for (int j = w; j < S; j += 4) {   // ascending j per wave -> first-max kept
            const float* gp = target + (size_t)(b * S_FULL + j + 1) * D;
            float s = 0.f;
            for (int d = lane; d < D; d += 64) s += trow[d] * gp[d];
            #pragma unroll
            for (int m = 32; m > 0; m >>= 1) s += __shfl_xor(s, m);
            s *= inv_g[b * S + j];
            if (s > bv) { bv = s; bj = j; }
        }
        if (lane == 0) { wv[w] = bv; wj[w] = bj; }
        __syncthreads();
        if (t == 0) {
            float fv = wv[0]; int fj = wj[0];
            for (int q = 1; q < 4; ++q)
                if (wv[q] > fv || (wv[q] == fv && wj[q] < fj)) { fv = wv[q]; fj = wj[q]; }
            bjf = fj;
            idx_f[row] = (float)fj;
        }
        __syncthreads();
        if (pm[b * S_FULL + i + 1] == 0) {     // block-uniform branch
            const float* gp = target + (size_t)(b * S_FULL + bjf + 1) * D;
            float s = 0.f;
            for (int d = t; d < D; d += 256) { float df = trow[d] - gp[d]; s += df * df; }
            #pragma unroll
            for (int m = 32; m > 0; m >>= 1) s += __shfl_xor(s, m);
            if (lane == 0) ls[w] = s;
            __syncthreads();
            if (t == 0) {
                atomicAdd(&acc[64  + (blockIdx.x & 63)], ls[0] + ls[1] + ls[2] + ls[3]);
                atomicAdd(&acc[128 + (blockIdx.x & 63)], 1.0f);
            }
        }
    }
}

// ---------------- 5. finalize ----------------
__global__ void finalize_kernel(const float* __restrict__ acc, float* __restrict__ out)
{
    int lane = threadIdx.x;   // 64 threads
    float si = acc[lane], st = acc[64 + lane], sc = acc[128 + lane];
    #pragma unroll
    for (int m = 32; m > 0; m >>= 1) {
        si += __shfl_xor(si, m);
        st += __shfl_xor(st, m);
        sc += __shfl_xor(sc, m);
    }
    if (lane == 0) {
        float img = si / (float)((size_t)B * S_FULL * D);
        float txt = st / (sc * (float)D);
        out[0] = 0.5f * (txt + img);
        out[1] = txt;
        out[2] = img;
    }
}

extern "C" void kernel_launch(void* const* d_in, const int* in_sizes, int n_in,
                              void* d_out, int out_size, void* d_ws, size_t ws_size,
                              hipStream_t stream) {
    const float* image  = (const float*)d_in[0];
    const float* text   = (const float*)d_in[1];
    const float* target = (const float*)d_in[2];
    const int*   pm     = (const int*)d_in[3];
    float* out = (float*)d_out;

    float* ws    = (float*)d_ws;
    float* inv_t = ws;                          // NROWS
    float* inv_g = ws + NROWS;                  // NROWS
    float* pv    = ws + 2 * NROWS;              // NROWS*4
    float* ps    = ws + 6 * NROWS;              // NROWS*4
    int*   pj    = (int*)(ws + 10 * NROWS);     // NROWS*4
    int*   list  = (int*)(ws + 14 * NROWS);     // NROWS
    int*   cnt   = (int*)(ws + 15 * NROWS);     // 1 (+pad)
    float* acc   = ws + 15 * NROWS + 64;        // 192 slots

    hipMemsetAsync(ws + 15 * NROWS, 0, 256 * sizeof(float), stream);

    prep_kernel<<<B * S_FULL / 4, 256, 0, stream>>>(image, text, target, inv_t, inv_g, acc);
    simargmax_kernel<<<dim3(4, NCHUNK, B), 256, 0, stream>>>(
        text, target, inv_t, inv_g, pv, ps, pj);
    text_kernel<<<(NROWS + 3) / 4, 256, 0, stream>>>(
        text, target, pm, pv, ps, pj, out + 3, acc, list, cnt);
    recheck_kernel<<<120, 256, 0, stream>>>(
        text, target, pm, inv_g, list, cnt, out + 3, acc);
    finalize_kernel<<<1, 64, 0, stream>>>(acc, out);
}

// Round 6
// 355.577 us; speedup vs baseline: 8.5557x; 8.5557x over previous
//
#include <hip/hip_runtime.h>
#include <math.h>

#define B       32
#define S_FULL  512
#define S       511            // sliced length (drop token 0)
#define D       768
#define NROWS   (B * S)        // 16352

#define TM 128
#define TN 128
#define NCHUNK 4
#define NKT 24                 // D / 32
#define RSTR 72                // LDS row stride in halfwords (144 B, 16B-aligned)
#define EPS_MARGIN 6e-5f       // split-bf16 sim error <=1e-5 per sim; 3x safety on 2e-5

typedef __attribute__((ext_vector_type(8))) short bf16x8;   // 8 bf16 (4 VGPRs)
typedef __attribute__((ext_vector_type(4))) float f32x4;

__device__ inline unsigned short f2bf(float f) {
    union { float f; unsigned u; } c; c.f = f;
    unsigned u = c.u;
    return (unsigned short)((u + 0x7fffu + ((u >> 16) & 1u)) >> 16);   // RNE
}
__device__ inline float bf2f(unsigned short h) {
    union { unsigned u; float f; } c; c.u = ((unsigned)h) << 16;
    return c.f;
}
__device__ inline void split4(float x0, float x1, float x2, float x3,
                              short4& hi, short4& lo) {
    unsigned short h0 = f2bf(x0), h1 = f2bf(x1), h2 = f2bf(x2), h3 = f2bf(x3);
    hi = make_short4((short)h0, (short)h1, (short)h2, (short)h3);
    lo = make_short4((short)f2bf(x0 - bf2f(h0)), (short)f2bf(x1 - bf2f(h1)),
                     (short)f2bf(x2 - bf2f(h2)), (short)f2bf(x3 - bf2f(h3)));
}

// ---------------- 1. prep: row inv-norms + image loss (shares target read) --
__global__ __launch_bounds__(256) void prep_kernel(
    const float* __restrict__ image, const float* __restrict__ text,
    const float* __restrict__ target,
    float* __restrict__ inv_t, float* __restrict__ inv_g, float* __restrict__ acc)
{
    int row  = blockIdx.x * 4 + (threadIdx.x >> 6);   // 0..B*S_FULL-1
    int lane = threadIdx.x & 63;
    int b = row >> 9, i = row & 511;
    const float4* pi4 = (const float4*)(image  + (size_t)row * D);
    const float4* pt4 = (const float4*)(text   + (size_t)row * D);
    const float4* pg4 = (const float4*)(target + (size_t)row * D);
    float st = 0.f, sg = 0.f, si = 0.f;
    #pragma unroll
    for (int q = 0; q < 3; ++q) {
        float4 a = pt4[lane + 64 * q];
        float4 g = pg4[lane + 64 * q];
        float4 m = pi4[lane + 64 * q];
        st += a.x*a.x + a.y*a.y + a.z*a.z + a.w*a.w;
        sg += g.x*g.x + g.y*g.y + g.z*g.z + g.w*g.w;
        float dx = m.x-g.x, dy = m.y-g.y, dz = m.z-g.z, dw = m.w-g.w;
        si += dx*dx + dy*dy + dz*dz + dw*dw;
    }
    #pragma unroll
    for (int m = 32; m > 0; m >>= 1) {
        st += __shfl_xor(st, m); sg += __shfl_xor(sg, m); si += __shfl_xor(si, m);
    }
    if (lane == 0) {
        atomicAdd(&acc[blockIdx.x & 63], si);
        if (i >= 1) {
            int r = b * S + i - 1;
            inv_t[r] = (st > 0.f) ? 1.f / sqrtf(st) : 0.f;
            inv_g[r] = (sg > 0.f) ? 1.f / sqrtf(sg) : 0.f;
        }
    }
}

// ---------------- 2. split-bf16 MFMA GEMM + per-chunk top-2 ----------------
// grid (4, NCHUNK, B); block 256 (4 waves); block tile 128x128.
// Wave grid 4x1: wave w owns rows [w*32, w*32+32) x ALL 128 cols (one writer/slot).
__global__ __launch_bounds__(256, 2) void simargmax_kernel(
    const float* __restrict__ text, const float* __restrict__ target,
    const float* __restrict__ inv_t, const float* __restrict__ inv_g,
    float* __restrict__ pv, float* __restrict__ ps, int* __restrict__ pj)
{
    __shared__ __align__(16) short As[TM * RSTR];   // per row: [32 hi][32 lo] bf16
    __shared__ __align__(16) short Bs[TM * RSTR];

    const int i0 = blockIdx.x * TM;
    const int jc = blockIdx.y;
    const int j0 = jc * TN;
    const int b  = blockIdx.z;
    const int t  = threadIdx.x;
    const int lane = t & 63;
    const int wy = t >> 6;                    // wave row-strip 0..3
    const int quad = lane >> 4, cid = lane & 15;

    const float* Abase = text   + (size_t)b * S_FULL * D + D;   // skip token 0
    const float* Bbase = target + (size_t)b * S_FULL * D + D;

    // staging map: 8 lanes x float4 = 128B contiguous per row
    const int r0 = t >> 3;          // 0..31
    const int kq = (t & 7) * 4;     // 0..28

    float sa[4], sb[4];
    #pragma unroll
    for (int h = 0; h < 4; ++h) {
        int gi = i0 + r0 + h * 32;
        sa[h] = (gi < S) ? inv_t[b * S + gi] : 0.f;
        int gj = j0 + r0 + h * 32;
        sb[h] = (gj < S) ? inv_g[b * S + gj] : 0.f;
    }

    f32x4 acc[2][8];
    #pragma unroll
    for (int mt = 0; mt < 2; ++mt)
        #pragma unroll
        for (int nt = 0; nt < 8; ++nt)
            acc[mt][nt] = (f32x4){0.f, 0.f, 0.f, 0.f};

    for (int kt = 0; kt < NKT; ++kt) {
        const int k0 = kt * 32;
        float4 va[4], vb[4];
        #pragma unroll
        for (int h = 0; h < 4; ++h) {
            int gi = i0 + r0 + h * 32;
            va[h] = (gi < S) ? *(const float4*)(Abase + (size_t)gi * D + k0 + kq)
                             : make_float4(0.f, 0.f, 0.f, 0.f);
            int gj = j0 + r0 + h * 32;
            vb[h] = (gj < S) ? *(const float4*)(Bbase + (size_t)gj * D + k0 + kq)
                             : make_float4(0.f, 0.f, 0.f, 0.f);
        }
        __syncthreads();   // prior tile's ds_reads drained before overwrite
        #pragma unroll
        for (int h = 0; h < 4; ++h) {
            int row = r0 + h * 32;
            short4 ahi, alo, bhi, blo;
            split4(va[h].x * sa[h], va[h].y * sa[h], va[h].z * sa[h], va[h].w * sa[h], ahi, alo);
            split4(vb[h].x * sb[h], vb[h].y * sb[h], vb[h].z * sb[h], vb[h].w * sb[h], bhi, blo);
            *(short4*)&As[row * RSTR + kq]      = ahi;
            *(short4*)&As[row * RSTR + 32 + kq] = alo;
            *(short4*)&Bs[row * RSTR + kq]      = bhi;
            *(short4*)&Bs[row * RSTR + 32 + kq] = blo;
        }
        __syncthreads();

        bf16x8 ah[2], al[2];
        #pragma unroll
        for (int mt = 0; mt < 2; ++mt) {
            int ad = (wy * 32 + mt * 16 + cid) * RSTR + quad * 8;
            ah[mt] = *(const bf16x8*)&As[ad];
            al[mt] = *(const bf16x8*)&As[ad + 32];
        }
        #pragma unroll
        for (int nt = 0; nt < 8; ++nt) {
            int bd = (nt * 16 + cid) * RSTR + quad * 8;
            bf16x8 bh = *(const bf16x8*)&Bs[bd];
            bf16x8 bl = *(const bf16x8*)&Bs[bd + 32];
            #pragma unroll
            for (int mt = 0; mt < 2; ++mt) {
                acc[mt][nt] = __builtin_amdgcn_mfma_f32_16x16x32_bf16(ah[mt], bh, acc[mt][nt], 0, 0, 0);
                acc[mt][nt] = __builtin_amdgcn_mfma_f32_16x16x32_bf16(ah[mt], bl, acc[mt][nt], 0, 0, 0);
                acc[mt][nt] = __builtin_amdgcn_mfma_f32_16x16x32_bf16(al[mt], bh, acc[mt][nt], 0, 0, 0);
            }
        }
    }

    // epilogue: per-row top-2 over this chunk's 128 cols.
    // C/D layout: col = cid (within n-tile), row = quad*4 + reg (within m-tile)
    #pragma unroll
    for (int mt = 0; mt < 2; ++mt) {
        #pragma unroll
        for (int r = 0; r < 4; ++r) {
            float v1 = -INFINITY, v2 = -INFINITY; int j1 = -1;
            #pragma unroll
            for (int nt = 0; nt < 8; ++nt) {
                int col = j0 + nt * 16 + cid;
                float v = acc[mt][nt][r];
                if (col < S) {
                    if (v > v1) { v2 = v1; v1 = v; j1 = col; }
                    else if (v > v2) v2 = v;
                }
            }
            #pragma unroll
            for (int m = 1; m < 16; m <<= 1) {
                float ov1 = __shfl_xor(v1, m);
                int   oj1 = __shfl_xor(j1, m);
                float ov2 = __shfl_xor(v2, m);
                if (ov1 > v1) { v2 = fmaxf(v1, ov2); v1 = ov1; j1 = oj1; }
                else          { v2 = fmaxf(v2, ov1); }
            }
            if (cid == 0) {
                int gi = i0 + wy * 32 + mt * 16 + quad * 4 + r;
                if (gi < S) {
                    size_t o = ((size_t)(b * S + gi) << 2) + jc;
                    pv[o] = v1; ps[o] = v2; pj[o] = j1;
                }
            }
        }
    }
}

// ---------------- 3. combine chunks; commit or flag; text loss ----------------
__global__ __launch_bounds__(256) void text_kernel(
    const float* __restrict__ text, const float* __restrict__ target,
    const int* __restrict__ pm,
    const float* __restrict__ pv, const float* __restrict__ ps, const int* __restrict__ pj,
    float* __restrict__ idx_f, float* __restrict__ acc,
    int* __restrict__ list, int* __restrict__ cnt)
{
    int row = blockIdx.x * 4 + (threadIdx.x >> 6);
    if (row >= NROWS) return;
    int lane = threadIdx.x & 63;
    int b = row / S, i = row - b * S;

    float v1 = -INFINITY, v2 = -INFINITY; int j1 = 0;
    #pragma unroll
    for (int c = 0; c < NCHUNK; ++c) {
        size_t o = ((size_t)row << 2) + c;
        float a1 = pv[o], a2 = ps[o]; int aj = pj[o];
        if (a1 > v1) { v2 = fmaxf(v1, a2); v1 = a1; j1 = aj; }
        else         { v2 = fmaxf(v2, a1); }
    }
    if (v1 - v2 < EPS_MARGIN) {          // too close for split-bf16: exact recheck
        if (lane == 0) { int p = atomicAdd(cnt, 1); list[p] = row; }
        return;
    }
    if (lane == 0) idx_f[row] = (float)j1;

    if (pm[b * S_FULL + i + 1] != 0) return;
    const float4* pt = (const float4*)(text   + (size_t)(b * S_FULL + i  + 1) * D);
    const float4* pg = (const float4*)(target + (size_t)(b * S_FULL + j1 + 1) * D);
    float s = 0.f;
    #pragma unroll
    for (int q = 0; q < 3; ++q) {
        float4 a = pt[lane + 64 * q];
        float4 g = pg[lane + 64 * q];
        float dx = a.x-g.x, dy = a.y-g.y, dz = a.z-g.z, dw = a.w-g.w;
        s += dx*dx + dy*dy + dz*dz + dw*dw;
    }
    #pragma unroll
    for (int m = 32; m > 0; m >>= 1) s += __shfl_xor(s, m);
    if (lane == 0) {
        atomicAdd(&acc[64  + (blockIdx.x & 63)], s);
        atomicAdd(&acc[128 + (blockIdx.x & 63)], 1.0f);
    }
}

// ---------------- 4. exact fp32 argmax re-check (throughput-shaped) ----------
// block per flagged row (grid-stride). Text row cached in 12 regs/lane;
// per j: 3 coalesced float4 loads + 12 FMAs; 2 j's unrolled to overlap latency.
__global__ __launch_bounds__(256) void recheck_kernel(
    const float* __restrict__ text, const float* __restrict__ target,
    const int* __restrict__ pm, const float* __restrict__ inv_g,
    const int* __restrict__ list, const int* __restrict__ cnt,
    float* __restrict__ idx_f, float* __restrict__ acc)
{
    __shared__ float wv[4];
    __shared__ int   wj[4];
    __shared__ int   bjf;
    const int t = threadIdx.x, w = t >> 6, lane = t & 63;
    const int n = *cnt;
    for (int it = blockIdx.x; it < n; it += gridDim.x) {
        int row = list[it];
        int b = row / S, i = row - b * S;
        const float4* tp = (const float4*)(text + (size_t)(b * S_FULL + i + 1) * D);
        float4 tr0 = tp[lane], tr1 = tp[lane + 64], tr2 = tp[lane + 128];
        const float* Gb = target + (size_t)b * S_FULL * D + D;
        const float* ig = inv_g + b * S;

        float bv = -INFINITY; int bj = 0;
        for (int j = w; j < S; j += 8) {       // wave w: j ≡ w (mod 4), 2 per iter
            const float4* g0 = (const float4*)(Gb + (size_t)j * D);
            int j2 = j + 4; bool ok2 = (j2 < S);
            const float4* g1 = (const float4*)(Gb + (size_t)(ok2 ? j2 : j) * D);
            float4 a0 = g0[lane], a1 = g0[lane + 64], a2 = g0[lane + 128];
            float4 c0 = g1[lane], c1 = g1[lane + 64], c2 = g1[lane + 128];
            float s0 = tr0.x*a0.x + tr0.y*a0.y + tr0.z*a0.z + tr0.w*a0.w
                     + tr1.x*a1.x + tr1.y*a1.y + tr1.z*a1.z + tr1.w*a1.w
                     + tr2.x*a2.x + tr2.y*a2.y + tr2.z*a2.z + tr2.w*a2.w;
            float s1 = tr0.x*c0.x + tr0.y*c0.y + tr0.z*c0.z + tr0.w*c0.w
                     + tr1.x*c1.x + tr1.y*c1.y + tr1.z*c1.z + tr1.w*c1.w
                     + tr2.x*c2.x + tr2.y*c2.y + tr2.z*c2.z + tr2.w*c2.w;
            #pragma unroll
            for (int m = 32; m > 0; m >>= 1) {
                s0 += __shfl_xor(s0, m);
                s1 += __shfl_xor(s1, m);
            }
            s0 *= ig[j];
            if (s0 > bv) { bv = s0; bj = j; }       // ascending j: first-max kept
            if (ok2) {
                s1 *= ig[j2];
                if (s1 > bv) { bv = s1; bj = j2; }
            }
        }
        if (lane == 0) { wv[w] = bv; wj[w] = bj; }
        __syncthreads();
        if (t == 0) {
            float fv = wv[0]; int fj = wj[0];
            #pragma unroll
            for (int q = 1; q < 4; ++q)
                if (wv[q] > fv || (wv[q] == fv && wj[q] < fj)) { fv = wv[q]; fj = wj[q]; }
            bjf = fj;
            idx_f[row] = (float)fj;
        }
        __syncthreads();
        if (w == 0 && pm[b * S_FULL + i + 1] == 0) {
            const float4* gp = (const float4*)(Gb + (size_t)bjf * D);
            float4 a0 = gp[lane], a1 = gp[lane + 64], a2 = gp[lane + 128];
            float dx, s = 0.f;
            dx = tr0.x-a0.x; s += dx*dx;  dx = tr0.y-a0.y; s += dx*dx;
            dx = tr0.z-a0.z; s += dx*dx;  dx = tr0.w-a0.w; s += dx*dx;
            dx = tr1.x-a1.x; s += dx*dx;  dx = tr1.y-a1.y; s += dx*dx;
            dx = tr1.z-a1.z; s += dx*dx;  dx = tr1.w-a1.w; s += dx*dx;
            dx = tr2.x-a2.x; s += dx*dx;  dx = tr2.y-a2.y; s += dx*dx;
            dx = tr2.z-a2.z; s += dx*dx;  dx = tr2.w-a2.w; s += dx*dx;
            #pragma unroll
            for (int m = 32; m > 0; m >>= 1) s += __shfl_xor(s, m);
            if (lane == 0) {
                atomicAdd(&acc[64  + (blockIdx.x & 63)], s);
                atomicAdd(&acc[128 + (blockIdx.x & 63)], 1.0f);
            }
        }
        __syncthreads();
    }
}

// ---------------- 5. finalize ----------------
__global__ void finalize_kernel(const float* __restrict__ acc, float* __restrict__ out)
{
    int lane = threadIdx.x;   // 64 threads
    float si = acc[lane], st = acc[64 + lane], sc = acc[128 + lane];
    #pragma unroll
    for (int m = 32; m > 0; m >>= 1) {
        si += __shfl_xor(si, m);
        st += __shfl_xor(st, m);
        sc += __shfl_xor(sc, m);
    }
    if (lane == 0) {
        float img = si / (float)((size_t)B * S_FULL * D);
        float txt = st / (sc * (float)D);
        out[0] = 0.5f * (txt + img);
        out[1] = txt;
        out[2] = img;
    }
}

extern "C" void kernel_launch(void* const* d_in, const int* in_sizes, int n_in,
                              void* d_out, int out_size, void* d_ws, size_t ws_size,
                              hipStream_t stream) {
    const float* image  = (const float*)d_in[0];
    const float* text   = (const float*)d_in[1];
    const float* target = (const float*)d_in[2];
    const int*   pm     = (const int*)d_in[3];
    float* out = (float*)d_out;

    float* ws    = (float*)d_ws;
    float* inv_t = ws;                          // NROWS
    float* inv_g = ws + NROWS;                  // NROWS
    float* pv    = ws + 2 * NROWS;              // NROWS*4
    float* ps    = ws + 6 * NROWS;              // NROWS*4
    int*   pj    = (int*)(ws + 10 * NROWS);     // NROWS*4
    int*   list  = (int*)(ws + 14 * NROWS);     // NROWS
    int*   cnt   = (int*)(ws + 15 * NROWS);     // 1 (+pad)
    float* acc   = ws + 15 * NROWS + 64;        // 192 slots

    hipMemsetAsync(ws + 15 * NROWS, 0, 256 * sizeof(float), stream);

    prep_kernel<<<B * S_FULL / 4, 256, 0, stream>>>(image, text, target, inv_t, inv_g, acc);
    simargmax_kernel<<<dim3(4, NCHUNK, B), 256, 0, stream>>>(
        text, target, inv_t, inv_g, pv, ps, pj);
    text_kernel<<<(NROWS + 3) / 4, 256, 0, stream>>>(
        text, target, pm, pv, ps, pj, out + 3, acc, list, cnt);
    recheck_kernel<<<512, 256, 0, stream>>>(
        text, target, pm, inv_g, list, cnt, out + 3, acc);
    finalize_kernel<<<1, 64, 0, stream>>>(acc, out);
}